// Round 2
// baseline (1338.569 us; speedup 1.0000x reference)
//
#include <hip/hip_runtime.h>
#include <hip/hip_bf16.h>
#include <stdint.h>
#include <math.h>

#define T_TOKENS 16384
#define DIM      512
#define NEXP     8
#define HID      2048

typedef __attribute__((ext_vector_type(8))) __bf16 bf16x8;
typedef __attribute__((ext_vector_type(4))) __bf16 bf16x4;
typedef __attribute__((ext_vector_type(16))) float f32x16;

__device__ __forceinline__ f32x16 mfma32(bf16x8 a, bf16x8 b, f32x16 c) {
  return __builtin_amdgcn_mfma_f32_32x32x16_bf16(a, b, c, 0, 0, 0);
}

// async global->LDS, 16B per lane; lds dest must be wave-uniform base (+lane*16 implicit)
__device__ __forceinline__ void glds16(const __bf16* g, __bf16* l) {
  __builtin_amdgcn_global_load_lds((const __attribute__((address_space(1))) void*)g,
                                   (__attribute__((address_space(3))) void*)l, 16, 0, 0);
}

// ---- JAX threefry2x32, key = (0, 42) ----
__device__ __forceinline__ void threefry2x32(uint32_t k0, uint32_t k1,
                                             uint32_t x0, uint32_t x1,
                                             uint32_t* o0, uint32_t* o1) {
  uint32_t ks0 = k0, ks1 = k1, ks2 = k0 ^ k1 ^ 0x1BD11BDAu;
#define TF_ROT(v, d) (((v) << (d)) | ((v) >> (32 - (d))))
#define TF_ROUND(r) { x0 += x1; x1 = TF_ROT(x1, r); x1 ^= x0; }
  x0 += ks0; x1 += ks1;
  TF_ROUND(13) TF_ROUND(15) TF_ROUND(26) TF_ROUND(6)
  x0 += ks1; x1 += ks2 + 1u;
  TF_ROUND(17) TF_ROUND(29) TF_ROUND(16) TF_ROUND(24)
  x0 += ks2; x1 += ks0 + 2u;
  TF_ROUND(13) TF_ROUND(15) TF_ROUND(26) TF_ROUND(6)
  x0 += ks0; x1 += ks1 + 3u;
  TF_ROUND(17) TF_ROUND(29) TF_ROUND(16) TF_ROUND(24)
  x0 += ks1; x1 += ks2 + 4u;
  TF_ROUND(13) TF_ROUND(15) TF_ROUND(26) TF_ROUND(6)
  x0 += ks2; x1 += ks0 + 5u;
#undef TF_ROUND
#undef TF_ROT
  *o0 = x0; *o1 = x1;
}

// ---- XLA ErfInv32 (Giles polynomial) ----
__device__ __forceinline__ float erfinv_xla(float x) {
  float w = -log1pf(__fmul_rn(-x, x));
  float p;
  if (w < 5.0f) {
    w = __fadd_rn(w, -2.5f);
    p = 2.81022636e-08f;
    p = __fadd_rn(3.43273939e-07f, __fmul_rn(p, w));
    p = __fadd_rn(-3.5233877e-06f, __fmul_rn(p, w));
    p = __fadd_rn(-4.39150654e-06f, __fmul_rn(p, w));
    p = __fadd_rn(0.00021858087f, __fmul_rn(p, w));
    p = __fadd_rn(-0.00125372503f, __fmul_rn(p, w));
    p = __fadd_rn(-0.00417768164f, __fmul_rn(p, w));
    p = __fadd_rn(0.246640727f, __fmul_rn(p, w));
    p = __fadd_rn(1.50140941f, __fmul_rn(p, w));
  } else {
    w = __fadd_rn(sqrtf(w), -3.0f);
    p = -0.000200214257f;
    p = __fadd_rn(0.000100950558f, __fmul_rn(p, w));
    p = __fadd_rn(0.00134934322f, __fmul_rn(p, w));
    p = __fadd_rn(-0.00367342844f, __fmul_rn(p, w));
    p = __fadd_rn(0.00573950773f, __fmul_rn(p, w));
    p = __fadd_rn(-0.0076224613f, __fmul_rn(p, w));
    p = __fadd_rn(0.00943887047f, __fmul_rn(p, w));
    p = __fadd_rn(1.00167406f, __fmul_rn(p, w));
    p = __fadd_rn(2.83297682f, __fmul_rn(p, w));
  }
  return __fmul_rn(p, x);
}

__device__ __forceinline__ float jax_normal_at(uint32_t i) {
  uint32_t o0, o1;
  threefry2x32(0u, 42u, 0u, i, &o0, &o1);
  uint32_t bits = o0 ^ o1;
  float f = __fadd_rn(__uint_as_float((bits >> 9) | 0x3f800000u), -1.0f);
  const float lo = -0.99999994f;
  float u = fmaxf(lo, __fadd_rn(__fmul_rn(f, 2.0f), lo));
  return __fmul_rn(1.4142135623730951f, erfinv_xla(u));
}

// ---------------- Router: 4 tokens per wave, 16 lanes per token ----------------
// fp64 accumulation (numerically equivalent to prior passing version), W staged
// in LDS once per block with +8-floats-per-32-rows padding (kills 16-way conflicts).
__global__ __launch_bounds__(256) void router_kernel(
    const float* __restrict__ x, const float* __restrict__ Wr, const float* __restrict__ br,
    const float* __restrict__ Wn, const float* __restrict__ bn,
    int* __restrict__ counts, int* __restrict__ top_i, float* __restrict__ top_g) {
  __shared__ float WrS[4224], WnS[4224];   // 512*8 + 16*8 pad
  const int tid = threadIdx.x;
#pragma unroll
  for (int i = 0; i < 4; ++i) {
    int i4 = tid + i * 256;                // float4 index 0..1023
    int d = i4 >> 1, eh = (i4 & 1) * 4;
    float4 vr = ((const float4*)Wr)[i4];
    float4 vn = ((const float4*)Wn)[i4];
    *(float4*)&WrS[d * 8 + (d >> 5) * 8 + eh] = vr;
    *(float4*)&WnS[d * 8 + (d >> 5) * 8 + eh] = vn;
  }
  __syncthreads();

  const int w = tid >> 6, lane = tid & 63;
  const int tl = lane & 3, dq = lane >> 2;     // token-in-wave, d-slice
  const int t = blockIdx.x * 16 + w * 4 + tl;

  const float* xp = x + (size_t)t * DIM + dq * 32;
  float xv[32];
#pragma unroll
  for (int i = 0; i < 8; ++i) {
    float4 f = *(const float4*)(xp + i * 4);
    xv[i * 4 + 0] = f.x; xv[i * 4 + 1] = f.y; xv[i * 4 + 2] = f.z; xv[i * 4 + 3] = f.w;
  }

  double accR[8], accN[8];
#pragma unroll
  for (int e2 = 0; e2 < 8; ++e2) { accR[e2] = 0.0; accN[e2] = 0.0; }

#pragma unroll
  for (int r = 0; r < 32; ++r) {
    int d = dq * 32 + r;
    const float* wr = &WrS[d * 8 + (d >> 5) * 8];
    const float* wn = &WnS[d * 8 + (d >> 5) * 8];
    double xd = (double)xv[r];
#pragma unroll
    for (int e2 = 0; e2 < 8; ++e2) {
      accR[e2] += xd * (double)wr[e2];
      accN[e2] += xd * (double)wn[e2];
    }
  }
  // reduce across the 16 lanes of each token (xor 4,8,16,32)
#pragma unroll
  for (int m = 4; m <= 32; m <<= 1) {
#pragma unroll
    for (int e2 = 0; e2 < 8; ++e2) {
      accR[e2] += __shfl_xor(accR[e2], m);
      accN[e2] += __shfl_xor(accN[e2], m);
    }
  }

  // pointwise: lanes 0..31 handle (token = lane&3, expert = lane>>2)
  const int el = (lane >> 2) & 7;
  double accRm = 0.0, accNm = 0.0;
#pragma unroll
  for (int e2 = 0; e2 < 8; ++e2) {
    double vR = __shfl(accR[e2], tl);
    double vN = __shfl(accN[e2], tl);
    if (e2 == el) { accRm = vR; accNm = vN; }
  }
  double noisy = -1.0e308;
  if (lane < 32) {
    double logit = accRm + (double)br[el];
    double nlin  = accNm + (double)bn[el];
    double noise = (double)jax_normal_at((uint32_t)t * 8u + (uint32_t)el);
    double sp = fmax(nlin, 0.0) + log1p(exp(-fabs(nlin)));
    noisy = logit + noise * sp;
  }
  double v[8];
#pragma unroll
  for (int e2 = 0; e2 < 8; ++e2) v[e2] = __shfl(noisy, tl + 4 * e2);

  if (lane < 4) {
    int i1 = 0; double v1 = v[0];
#pragma unroll
    for (int e2 = 1; e2 < 8; ++e2) if (v[e2] > v1) { v1 = v[e2]; i1 = e2; }
    int i2 = -1; double v2 = -1.0e308;
#pragma unroll
    for (int e2 = 0; e2 < 8; ++e2) if (e2 != i1 && v[e2] > v2) { v2 = v[e2]; i2 = e2; }
    double w2 = exp(v2 - v1);
    double s = 1.0 + w2;
    float g1 = (float)(1.0 / s), g2 = (float)(w2 / s);
    top_i[t * 2 + 0] = i1; top_g[t * 2 + 0] = g1;
    top_i[t * 2 + 1] = i2; top_g[t * 2 + 1] = g2;
    atomicAdd(&counts[i1], 1);
    atomicAdd(&counts[i2], 1);
  }
}

// offsets aligned to 64 so 64-token tiles never span experts
__global__ void scan_kernel(const int* __restrict__ counts, int* __restrict__ offsets) {
  if (threadIdx.x == 0 && blockIdx.x == 0) {
    int s = 0;
#pragma unroll
    for (int e = 0; e < NEXP; ++e) { offsets[e] = s; s += (counts[e] + 63) & ~63; }
  }
}

__global__ __launch_bounds__(256) void scatter_kernel(
    const int* __restrict__ top_i, const float* __restrict__ top_g,
    const int* __restrict__ offsets, int* __restrict__ fill,
    int* __restrict__ ltok, float* __restrict__ lgate) {
  int i = blockIdx.x * 256 + threadIdx.x;
  int e = top_i[i];
  float g = top_g[i];
  int pos = atomicAdd(&fill[e], 1);
  int dst = offsets[e] + pos;
  ltok[dst] = i >> 1;
  lgate[dst] = g;
}

// ---- transpose-pack for 32-wide MFMA fragment tiles:
// src [e][R][C] fp32 -> dst [e][C/32][R/8][32][8] bf16
// dst[e][nt][ko][lc][j] = src[e][ko*8+j][nt*32+lc]
__global__ __launch_bounds__(256) void pack_bfrag32(const float* __restrict__ src,
                                                    __bf16* __restrict__ dst,
                                                    int R, int C) {
  int nct = C >> 6;
  int tilesPerE = (R >> 6) * nct;
  int e = blockIdx.x / tilesPerE;
  int rem = blockIdx.x % tilesPerE;
  int rt = rem / nct, ct = rem % nct;

  __shared__ float Ls[64][68];

  const float* s = src + (size_t)e * R * C + (size_t)(rt * 64) * C + ct * 64;
  int row = threadIdx.x >> 4;
  int col = (threadIdx.x & 15) * 4;
#pragma unroll
  for (int it = 0; it < 4; ++it) {
    float4 v = *(const float4*)(s + (size_t)(it * 16 + row) * C + col);
    *(float4*)&Ls[it * 16 + row][col] = v;
  }
  __syncthreads();

  int KO = R >> 3;
#pragma unroll
  for (int q = 0; q < 2; ++q) {
    int f = threadIdx.x + q * 256;
    int lc = f & 31;
    int kol = (f >> 5) & 7;
    int ntl = f >> 8;
    bf16x8 v;
#pragma unroll
    for (int j = 0; j < 8; ++j) v[j] = (__bf16)Ls[kol * 8 + j][ntl * 32 + lc];
    size_t idx = ((size_t)(e * (C >> 5) + ct * 2 + ntl) * KO + rt * 8 + kol) * 256 + lc * 8;
    *(bf16x8*)(dst + idx) = v;
  }
}

// ---------------- Fused MFMA expert FFN v3 ------------------------------------
// M=64 tokens/block, 8 waves, swapped MFMA operands (A=weight frag entity=out-col,
// B=X/H frag entity=token => C col = token). Weights streamed through LDS with
// global_load_lds (16B) in a 2-phase double-buffered pipeline: 128 stages of 32KB
// per tile (64 GEMM1 + 64 GEMM2, interleaved per hid-chunk of 128).
__global__ __launch_bounds__(512) void expert_mfma(
    const float* __restrict__ x,
    const __bf16* __restrict__ W1p, const float* __restrict__ b1,
    const __bf16* __restrict__ W2p, const float* __restrict__ b2,
    const int* __restrict__ counts, const int* __restrict__ offsets,
    const int* __restrict__ ltok, const float* __restrict__ lgate,
    float* __restrict__ out) {
  const int e = blockIdx.x & 7;          // XCD-pinned expert
  const int tslot = blockIdx.x >> 3;     // 0..63
  const int cnt = counts[e];

  __shared__ __bf16 Xs[64 * 64 * 8];     // 64 KB: [tok][ koX ^ (tok&7) ][j]
  __shared__ __bf16 Wb[2][16384];        // 2 x 32 KB weight stage buffers
  __shared__ __bf16 Hs[64 * 16 * 8];     // 16 KB: [tok][ koH ^ (tok&7) ][j]
  __shared__ int   toks[64];
  __shared__ float gates[64];

  const int tid  = threadIdx.x;
  const int lane = tid & 63;
  const int w    = tid >> 6;             // 0..7
  const int hi   = lane >> 5;
  const int lm   = lane & 31;
  const int wh   = w >> 1;               // G1 hid 32-tile / G2 d-quarter
  const int wt   = w & 1;                // token half
  const int tok  = wt * 32 + lm;
  const int t7   = lm & 7;

  const __bf16* W1e = W1p + (size_t)e * (64 * 64 * 256);
  const __bf16* W2e = W2p + (size_t)e * (16 * 256 * 256);

  // stage s (0..127): hc = s>>3; sub = s&7; sub<4 -> GEMM1 kc=sub ; else GEMM2 q2=sub-4
  auto issue = [&](int s, int buf) {
    int hc = s >> 3, sub = s & 7;
    char* ldsB = (char*)&Wb[buf][0];
    if (sub < 4) {
      int kc = sub;
      int nt_l = w >> 1;
#pragma unroll
      for (int q = 0; q < 4; ++q) {
        int ko_l = (w & 1) * 8 + q * 2;
        size_t gelem = (((size_t)(hc * 4 + nt_l) * 64) + (size_t)(kc * 16 + ko_l)) * 256;
        glds16(W1e + gelem + lane * 8, (__bf16*)(ldsB + (nt_l * 16 + ko_l) * 512));
      }
    } else {
      int q2 = sub - 4;
#pragma unroll
      for (int q = 0; q < 4; ++q) {
        int nt2 = w * 2 + (q >> 1);
        int kb  = (q & 1) * 2;
        size_t gelem = (((size_t)nt2 * 256) + (size_t)(hc * 16 + q2 * 4 + kb)) * 256;
        glds16(W2e + gelem + lane * 8, (__bf16*)(ldsB + (nt2 * 4 + kb) * 512));
      }
    }
  };

  for (int tile = tslot; tile * 64 < cnt; tile += 64) {
    int start = tile * 64;
    int nrow = min(64, cnt - start);
    int base = offsets[e] + start;

    __syncthreads();                     // prev tile fully done with LDS
    issue(0, 0);                         // fire first weight stage early
    if (tid < 64) {
      int tk = 0; float g = 0.f;
      if (tid < nrow) { tk = ltok[base + tid]; g = lgate[base + tid]; }
      toks[tid] = tk; gates[tid] = g;
    }
    __syncthreads();                     // toks visible

    // stage X tile: fp32 global -> bf16 LDS (B-frag layout, XOR-swizzled)
    {
      int tm = tid >> 3, seg = tid & 7;
      bool valid = tm < nrow;
      const float* xp = x + (size_t)(valid ? toks[tm] : 0) * DIM + seg * 64;
#pragma unroll
      for (int ss = 0; ss < 8; ++ss) {
        bf16x8 v;
        if (valid) {
          float4 f0 = *(const float4*)(xp + ss * 8);
          float4 f1 = *(const float4*)(xp + ss * 8 + 4);
          v[0] = (__bf16)f0.x; v[1] = (__bf16)f0.y; v[2] = (__bf16)f0.z; v[3] = (__bf16)f0.w;
          v[4] = (__bf16)f1.x; v[5] = (__bf16)f1.y; v[6] = (__bf16)f1.z; v[7] = (__bf16)f1.w;
        } else {
#pragma unroll
          for (int j = 0; j < 8; ++j) v[j] = (__bf16)0.f;
        }
        int ko = seg * 8 + ss;
        *(bf16x8*)((char*)Xs + ((size_t)tm * 64 + (ko ^ (tm & 7))) * 16) = v;
      }
    }

    f32x16 acc2[4];
#pragma unroll
    for (int ntl = 0; ntl < 4; ++ntl)
#pragma unroll
      for (int r = 0; r < 16; ++r) acc2[ntl][r] = 0.f;
    f32x16 acc1;

    __syncthreads();                     // Xs ready + stage0 landed (vmcnt drained)

    for (int s = 0; s < 128; ++s) {
      if (s + 1 < 128) issue(s + 1, (s + 1) & 1);
      int hc = s >> 3, sub = s & 7;
      const char* ldsB = (const char*)&Wb[s & 1][0];

      if (sub < 4) {                     // ---- GEMM1 k-chunk ----
        if (sub == 0) {
#pragma unroll
          for (int r = 0; r < 16; ++r) acc1[r] = 0.f;
        }
        int kc = sub;
#pragma unroll
        for (int kss = 0; kss < 8; ++kss) {
          bf16x8 a = *(const bf16x8*)(ldsB + (wh * 16 + kss * 2 + hi) * 512 + lm * 16);
          int koX = kc * 16 + kss * 2 + hi;
          bf16x8 bx = *(const bf16x8*)((const char*)Xs + ((size_t)tok * 64 + (koX ^ t7)) * 16);
          acc1 = mfma32(a, bx, acc1);
        }
        if (sub == 3) {                  // H epilogue: bias+relu -> Hs (b64 stores)
#pragma unroll
          for (int q = 0; q < 4; ++q) {
            bf16x4 pk;
#pragma unroll
            for (int rr = 0; rr < 4; ++rr) {
              int hid_l = wh * 32 + rr + 8 * q + 4 * hi;
              float bias = b1[e * HID + hc * 128 + hid_l];
              pk[rr] = (__bf16)fmaxf(acc1[q * 4 + rr] + bias, 0.f);
            }
            int koH = wh * 4 + q;
            *(bf16x4*)((char*)Hs + ((size_t)tok * 16 + (koH ^ t7)) * 16 + hi * 8) = pk;
          }
        }
      } else {                           // ---- GEMM2 sub-chunk ----
        int q2 = sub - 4;
#pragma unroll
        for (int kss = 0; kss < 2; ++kss) {
          int koH = q2 * 4 + kss * 2 + hi;
          bf16x8 bh = *(const bf16x8*)((const char*)Hs + ((size_t)tok * 16 + (koH ^ t7)) * 16);
#pragma unroll
          for (int ntl = 0; ntl < 4; ++ntl) {
            bf16x8 a = *(const bf16x8*)(ldsB + ((wh * 4 + ntl) * 4 + kss * 2 + hi) * 512 + lm * 16);
            acc2[ntl] = mfma32(a, bh, acc2[ntl]);
          }
        }
      }
      __syncthreads();
    }

    // epilogue: gate-weighted atomic accumulate (per-lane token!)
    {
      int tk = toks[tok];
      float g = gates[tok];
      float* op = out + (size_t)tk * DIM;
#pragma unroll
      for (int ntl = 0; ntl < 4; ++ntl) {
        int dbase = (wh * 4 + ntl) * 32 + 4 * hi;
#pragma unroll
        for (int q = 0; q < 4; ++q)
#pragma unroll
          for (int rr = 0; rr < 4; ++rr) {
            int d = dbase + rr + 8 * q;
            atomicAdd(op + d, g * (acc2[ntl][q * 4 + rr] + b2[e * DIM + d]));
          }
      }
    }
  }
}

extern "C" void kernel_launch(void* const* d_in, const int* in_sizes, int n_in,
                              void* d_out, int out_size, void* d_ws, size_t ws_size,
                              hipStream_t stream) {
  const float* x  = (const float*)d_in[0];
  const float* Wr = (const float*)d_in[1];
  const float* br = (const float*)d_in[2];
  const float* Wn = (const float*)d_in[3];
  const float* bn = (const float*)d_in[4];
  const float* W1 = (const float*)d_in[5];
  const float* b1 = (const float*)d_in[6];
  const float* W2 = (const float*)d_in[7];
  const float* b2 = (const float*)d_in[8];
  float* out = (float*)d_out;

  uint8_t* wsb = (uint8_t*)d_ws;
  int* counts   = (int*)(wsb);
  int* offsets  = (int*)(wsb + 32);
  int* fill     = (int*)(wsb + 64);
  int* top_i    = (int*)(wsb + 128);      // 131072 B
  float* top_g  = (float*)(wsb + 131200); // 131072 B
  int* ltok     = (int*)(wsb + 262272);   // 133120 B (33280 slots, 64-align pad)
  float* lgate  = (float*)(wsb + 395392); // 133120 B
  __bf16* W1p   = (__bf16*)(wsb + 528896);            // 16 MB
  __bf16* W2p   = (__bf16*)(wsb + 528896 + 16777216); // 16 MB
  // total ws usage: 528896 + 2*16777216 = 34,083,328 bytes (~34.1 MB)

  hipMemsetAsync(out, 0, (size_t)out_size * sizeof(float), stream);
  hipMemsetAsync(wsb, 0, 128, stream);

  pack_bfrag32<<<2048, 256, 0, stream>>>(W1, W1p, DIM, HID);
  pack_bfrag32<<<2048, 256, 0, stream>>>(W2, W2p, HID, DIM);
  router_kernel<<<T_TOKENS / 16, 256, 0, stream>>>(x, Wr, br, Wn, bn, counts, top_i, top_g);
  scan_kernel<<<1, 64, 0, stream>>>(counts, offsets);
  scatter_kernel<<<(2 * T_TOKENS) / 256, 256, 0, stream>>>(top_i, top_g, offsets, fill, ltok, lgate);
  expert_mfma<<<512, 512, 0, stream>>>(x, W1p, b1, W2p, b2, counts, offsets, ltok, lgate, out);
}

// Round 3
// 764.348 us; speedup vs baseline: 1.7513x; 1.7513x over previous
//
#include <hip/hip_runtime.h>
#include <hip/hip_bf16.h>
#include <stdint.h>
#include <math.h>

#define T_TOKENS 16384
#define DIM      512
#define NEXP     8
#define HID      2048

typedef __attribute__((ext_vector_type(8))) __bf16 bf16x8;
typedef __attribute__((ext_vector_type(16))) float f32x16;

__device__ __forceinline__ f32x16 mfma32(bf16x8 a, bf16x8 b, f32x16 c) {
  return __builtin_amdgcn_mfma_f32_32x32x16_bf16(a, b, c, 0, 0, 0);
}

// async global->LDS DMA, 16B/lane; LDS dest = wave-uniform base + lane*16
__device__ __forceinline__ void glds16(const __bf16* g, __bf16* l) {
  __builtin_amdgcn_global_load_lds((const __attribute__((address_space(1))) void*)g,
                                   (__attribute__((address_space(3))) void*)l, 16, 0, 0);
}

#define WAITVM(n) asm volatile("s_waitcnt vmcnt(" #n ")" ::: "memory")
#define WAITLGKM0 asm volatile("s_waitcnt lgkmcnt(0)" ::: "memory")
#define SBAR      asm volatile("s_barrier" ::: "memory")
#define SCHEDB    __builtin_amdgcn_sched_barrier(0)
#define ADV3(v)   v = ((v) == 2) ? 0 : ((v) + 1)

// ---- JAX threefry2x32, key = (0, 42) ----
__device__ __forceinline__ void threefry2x32(uint32_t k0, uint32_t k1,
                                             uint32_t x0, uint32_t x1,
                                             uint32_t* o0, uint32_t* o1) {
  uint32_t ks0 = k0, ks1 = k1, ks2 = k0 ^ k1 ^ 0x1BD11BDAu;
#define TF_ROT(v, d) (((v) << (d)) | ((v) >> (32 - (d))))
#define TF_ROUND(r) { x0 += x1; x1 = TF_ROT(x1, r); x1 ^= x0; }
  x0 += ks0; x1 += ks1;
  TF_ROUND(13) TF_ROUND(15) TF_ROUND(26) TF_ROUND(6)
  x0 += ks1; x1 += ks2 + 1u;
  TF_ROUND(17) TF_ROUND(29) TF_ROUND(16) TF_ROUND(24)
  x0 += ks2; x1 += ks0 + 2u;
  TF_ROUND(13) TF_ROUND(15) TF_ROUND(26) TF_ROUND(6)
  x0 += ks0; x1 += ks1 + 3u;
  TF_ROUND(17) TF_ROUND(29) TF_ROUND(16) TF_ROUND(24)
  x0 += ks1; x1 += ks2 + 4u;
  TF_ROUND(13) TF_ROUND(15) TF_ROUND(26) TF_ROUND(6)
  x0 += ks2; x1 += ks0 + 5u;
#undef TF_ROUND
#undef TF_ROT
  *o0 = x0; *o1 = x1;
}

// ---- XLA ErfInv32 (Giles polynomial) ----
__device__ __forceinline__ float erfinv_xla(float x) {
  float w = -log1pf(__fmul_rn(-x, x));
  float p;
  if (w < 5.0f) {
    w = __fadd_rn(w, -2.5f);
    p = 2.81022636e-08f;
    p = __fadd_rn(3.43273939e-07f, __fmul_rn(p, w));
    p = __fadd_rn(-3.5233877e-06f, __fmul_rn(p, w));
    p = __fadd_rn(-4.39150654e-06f, __fmul_rn(p, w));
    p = __fadd_rn(0.00021858087f, __fmul_rn(p, w));
    p = __fadd_rn(-0.00125372503f, __fmul_rn(p, w));
    p = __fadd_rn(-0.00417768164f, __fmul_rn(p, w));
    p = __fadd_rn(0.246640727f, __fmul_rn(p, w));
    p = __fadd_rn(1.50140941f, __fmul_rn(p, w));
  } else {
    w = __fadd_rn(sqrtf(w), -3.0f);
    p = -0.000200214257f;
    p = __fadd_rn(0.000100950558f, __fmul_rn(p, w));
    p = __fadd_rn(0.00134934322f, __fmul_rn(p, w));
    p = __fadd_rn(-0.00367342844f, __fmul_rn(p, w));
    p = __fadd_rn(0.00573950773f, __fmul_rn(p, w));
    p = __fadd_rn(-0.0076224613f, __fmul_rn(p, w));
    p = __fadd_rn(0.00943887047f, __fmul_rn(p, w));
    p = __fadd_rn(1.00167406f, __fmul_rn(p, w));
    p = __fadd_rn(2.83297682f, __fmul_rn(p, w));
  }
  return __fmul_rn(p, x);
}

__device__ __forceinline__ float jax_normal_at(uint32_t i) {
  uint32_t o0, o1;
  threefry2x32(0u, 42u, 0u, i, &o0, &o1);
  uint32_t bits = o0 ^ o1;
  float f = __fadd_rn(__uint_as_float((bits >> 9) | 0x3f800000u), -1.0f);
  const float lo = -0.99999994f;
  float u = fmaxf(lo, __fadd_rn(__fmul_rn(f, 2.0f), lo));
  return __fmul_rn(1.4142135623730951f, erfinv_xla(u));
}

// ---------------- Router: 4 tokens per wave, 16 lanes per token ----------------
__global__ __launch_bounds__(256) void router_kernel(
    const float* __restrict__ x, const float* __restrict__ Wr, const float* __restrict__ br,
    const float* __restrict__ Wn, const float* __restrict__ bn,
    int* __restrict__ counts, int* __restrict__ top_i, float* __restrict__ top_g) {
  __shared__ float WrS[4224], WnS[4224];   // 512*8 + 16*8 pad
  const int tid = threadIdx.x;
#pragma unroll
  for (int i = 0; i < 4; ++i) {
    int i4 = tid + i * 256;                // float4 index 0..1023
    int d = i4 >> 1, eh = (i4 & 1) * 4;
    float4 vr = ((const float4*)Wr)[i4];
    float4 vn = ((const float4*)Wn)[i4];
    *(float4*)&WrS[d * 8 + (d >> 5) * 8 + eh] = vr;
    *(float4*)&WnS[d * 8 + (d >> 5) * 8 + eh] = vn;
  }
  __syncthreads();

  const int w = tid >> 6, lane = tid & 63;
  const int tl = lane & 3, dq = lane >> 2;     // token-in-wave, d-slice
  const int t = blockIdx.x * 16 + w * 4 + tl;

  const float* xp = x + (size_t)t * DIM + dq * 32;
  float xv[32];
#pragma unroll
  for (int i = 0; i < 8; ++i) {
    float4 f = *(const float4*)(xp + i * 4);
    xv[i * 4 + 0] = f.x; xv[i * 4 + 1] = f.y; xv[i * 4 + 2] = f.z; xv[i * 4 + 3] = f.w;
  }

  double accR[8], accN[8];
#pragma unroll
  for (int e2 = 0; e2 < 8; ++e2) { accR[e2] = 0.0; accN[e2] = 0.0; }

#pragma unroll
  for (int r = 0; r < 32; ++r) {
    int d = dq * 32 + r;
    const float* wr = &WrS[d * 8 + (d >> 5) * 8];
    const float* wn = &WnS[d * 8 + (d >> 5) * 8];
    double xd = (double)xv[r];
#pragma unroll
    for (int e2 = 0; e2 < 8; ++e2) {
      accR[e2] += xd * (double)wr[e2];
      accN[e2] += xd * (double)wn[e2];
    }
  }
#pragma unroll
  for (int m = 4; m <= 32; m <<= 1) {
#pragma unroll
    for (int e2 = 0; e2 < 8; ++e2) {
      accR[e2] += __shfl_xor(accR[e2], m);
      accN[e2] += __shfl_xor(accN[e2], m);
    }
  }

  const int el = (lane >> 2) & 7;
  double accRm = 0.0, accNm = 0.0;
#pragma unroll
  for (int e2 = 0; e2 < 8; ++e2) {
    double vR = __shfl(accR[e2], tl);
    double vN = __shfl(accN[e2], tl);
    if (e2 == el) { accRm = vR; accNm = vN; }
  }
  double noisy = -1.0e308;
  if (lane < 32) {
    double logit = accRm + (double)br[el];
    double nlin  = accNm + (double)bn[el];
    double noise = (double)jax_normal_at((uint32_t)t * 8u + (uint32_t)el);
    double sp = fmax(nlin, 0.0) + log1p(exp(-fabs(nlin)));
    noisy = logit + noise * sp;
  }
  double v[8];
#pragma unroll
  for (int e2 = 0; e2 < 8; ++e2) v[e2] = __shfl(noisy, tl + 4 * e2);

  if (lane < 4) {
    int i1 = 0; double v1 = v[0];
#pragma unroll
    for (int e2 = 1; e2 < 8; ++e2) if (v[e2] > v1) { v1 = v[e2]; i1 = e2; }
    int i2 = -1; double v2 = -1.0e308;
#pragma unroll
    for (int e2 = 0; e2 < 8; ++e2) if (e2 != i1 && v[e2] > v2) { v2 = v[e2]; i2 = e2; }
    double w2 = exp(v2 - v1);
    double s = 1.0 + w2;
    float g1 = (float)(1.0 / s), g2 = (float)(w2 / s);
    top_i[t * 2 + 0] = i1; top_g[t * 2 + 0] = g1;
    top_i[t * 2 + 1] = i2; top_g[t * 2 + 1] = g2;
    atomicAdd(&counts[i1], 1);
    atomicAdd(&counts[i2], 1);
  }
}

// scatter with inline exclusive scan (offsets 64-aligned so tiles never span experts)
__global__ __launch_bounds__(256) void scatter_kernel(
    const int* __restrict__ top_i, const float* __restrict__ top_g,
    const int* __restrict__ counts, int* __restrict__ fill,
    int* __restrict__ ltok, float* __restrict__ lgate) {
  int i = blockIdx.x * 256 + threadIdx.x;
  int e = top_i[i];
  float g = top_g[i];
  int off = 0;
#pragma unroll
  for (int j = 0; j < NEXP; ++j) {
    int c = (counts[j] + 63) & ~63;
    if (j < e) off += c;
  }
  int pos = atomicAdd(&fill[e], 1);
  int dst = off + pos;
  ltok[dst] = i >> 1;
  lgate[dst] = g;
}

// ---- transpose-pack for 32-wide MFMA fragment tiles:
// src [e][R][C] fp32 -> dst [e][C/32][R/8][32][8] bf16
// dst[e][nt][ko][lc][j] = src[e][ko*8+j][nt*32+lc]
__global__ __launch_bounds__(256) void pack_bfrag32(const float* __restrict__ src,
                                                    __bf16* __restrict__ dst,
                                                    int R, int C) {
  int nct = C >> 6;
  int tilesPerE = (R >> 6) * nct;
  int e = blockIdx.x / tilesPerE;
  int rem = blockIdx.x % tilesPerE;
  int rt = rem / nct, ct = rem % nct;

  __shared__ float Ls[64][68];

  const float* s = src + (size_t)e * R * C + (size_t)(rt * 64) * C + ct * 64;
  int row = threadIdx.x >> 4;
  int col = (threadIdx.x & 15) * 4;
#pragma unroll
  for (int it = 0; it < 4; ++it) {
    float4 v = *(const float4*)(s + (size_t)(it * 16 + row) * C + col);
    *(float4*)&Ls[it * 16 + row][col] = v;
  }
  __syncthreads();

  int KO = R >> 3;
#pragma unroll
  for (int q = 0; q < 2; ++q) {
    int f = threadIdx.x + q * 256;
    int lc = f & 31;
    int kol = (f >> 5) & 7;
    int ntl = f >> 8;
    bf16x8 v;
#pragma unroll
    for (int j = 0; j < 8; ++j) v[j] = (__bf16)Ls[kol * 8 + j][ntl * 32 + lc];
    size_t idx = ((size_t)(e * (C >> 5) + ct * 2 + ntl) * KO + rt * 8 + kol) * 256 + lc * 8;
    *(bf16x8*)(dst + idx) = v;
  }
}

// ---------------- Fused MFMA expert FFN v4 ------------------------------------
// M=64 tokens/block, 8 waves. A = X/H frags (rows=tokens), B = weight frags
// (cols=d/hid) -> C col = output column -> coalesced atomic epilogue.
// Weights stream through WAVE-PRIVATE LDS rings (3 x 2KB/wave) via
// global_load_lds + counted s_waitcnt vmcnt(4) (never drained in-loop).
// Raw s_barrier (+lgkmcnt(0)) only at Hs handoffs -> DMA stays in flight.
__global__ __launch_bounds__(512) void expert_mfma(
    const float* __restrict__ x,
    const __bf16* __restrict__ W1p, const float* __restrict__ b1,
    const __bf16* __restrict__ W2p, const float* __restrict__ b2,
    const int* __restrict__ counts,
    const int* __restrict__ ltok, const float* __restrict__ lgate,
    float* __restrict__ out) {
  const int e = blockIdx.x & 7;          // XCD-pinned expert
  const int tslot = blockIdx.x >> 3;     // 0..63

  __shared__ __bf16 Xs[64 * 64 * 8];     // 64 KB  [tok][ko^(tok&31)][j]
  __shared__ __bf16 Hs[64 * 32 * 8];     // 32 KB  [tok][koH^(tok&31)][j]
  __shared__ __bf16 Ring[8][3][1024];    // 48 KB  wave-private DMA rings
  __shared__ int   toks[64];
  __shared__ float gates[64];

  const int tid  = threadIdx.x;
  const int lane = tid & 63;
  const int w    = tid >> 6;
  const int hi   = lane >> 5;
  const int lm   = lane & 31;

  int cnt = 0, off = 0;
#pragma unroll
  for (int j = 0; j < NEXP; ++j) {
    int c = counts[j];
    if (j == e) cnt = c;
    if (j < e) off += (c + 63) & ~63;
  }

  const __bf16* W1e = W1p + (size_t)e * (64 * 64 * 256);
  const __bf16* W2e = W2p + (size_t)e * (16 * 256 * 256);
  __bf16* ringW = &Ring[w][0][0];

  const float b2r0 = b2[e * DIM + (2 * w + 0) * 32 + lm];
  const float b2r1 = b2[e * DIM + (2 * w + 1) * 32 + lm];

  // sub-stage g (0..255): hc=g>>5, phase=(g>>4)&1, ss=g&15
  // G1: wave's n-tile nt=hc*8+w, 4 ko (2 k-steps)   G2: both nt2 {2w,2w+1}, 2 ko2 (1 k-step)
  auto issueStage = [&](int g, int slot) {
    int hc = g >> 5, ss = g & 15;
    __bf16* dst = ringW + slot * 1024;
    if (((g >> 4) & 1) == 0) {
      int nt = hc * 8 + w;
      const __bf16* src = W1e + ((size_t)(nt * 64 + ss * 4)) * 256 + lane * 8;
      glds16(src, dst);
      glds16(src + 512, dst + 512);
    } else {
      int ko2 = hc * 32 + ss * 2;
      glds16(W2e + ((size_t)((2 * w) * 256 + ko2)) * 256 + lane * 8, dst);
      glds16(W2e + ((size_t)((2 * w + 1) * 256 + ko2)) * 256 + lane * 8, dst + 512);
    }
  };

  for (int tile = tslot; tile * 64 < cnt; tile += 64) {
    int start = tile * 64;
    int nrow = min(64, cnt - start);
    int base = off + start;

    // fire this tile's first two weight stages (wave-private, safe pre-barrier)
    issueStage(0, 0);
    issueStage(1, 1);

    SBAR;                                // prev tile's epilogue done with toks/gates
    if (tid < 64) {
      int tk = 0; float g = 0.f;
      if (tid < nrow) { tk = ltok[base + tid]; g = lgate[base + tid]; }
      toks[tid] = tk; gates[tid] = g;
    }
    WAITLGKM0; SBAR;

    // stage X tile: fp32 global -> bf16 LDS (A-frag layout, 32-slot XOR swizzle)
    {
      int tm = tid >> 3, seg = tid & 7;
      bool valid = tm < nrow;
      const float* xp = x + (size_t)(valid ? toks[tm] : toks[0]) * DIM + seg * 64;
#pragma unroll
      for (int s2 = 0; s2 < 8; ++s2) {
        bf16x8 v;
        if (valid) {
          float4 f0 = *(const float4*)(xp + s2 * 8);
          float4 f1 = *(const float4*)(xp + s2 * 8 + 4);
          v[0] = (__bf16)f0.x; v[1] = (__bf16)f0.y; v[2] = (__bf16)f0.z; v[3] = (__bf16)f0.w;
          v[4] = (__bf16)f1.x; v[5] = (__bf16)f1.y; v[6] = (__bf16)f1.z; v[7] = (__bf16)f1.w;
        } else {
#pragma unroll
          for (int j = 0; j < 8; ++j) v[j] = (__bf16)0.f;
        }
        int ko = seg * 8 + s2;
        *(bf16x8*)&Xs[((size_t)tm * 64 + (ko ^ (tm & 31))) * 8] = v;
      }
    }
    WAITLGKM0; SBAR;                     // Xs ready (also implies stages 0,1 landed)

    f32x16 acc200, acc201, acc210, acc211;
#pragma unroll
    for (int r = 0; r < 16; ++r) { acc200[r] = 0.f; acc201[r] = 0.f; acc210[r] = 0.f; acc211[r] = 0.f; }

    int cs = 0, is_ = 2;

    for (int hc = 0; hc < 8; ++hc) {
      float bias = b1[e * HID + (hc * 8 + w) * 32 + lm];
      f32x16 acc10, acc11;
#pragma unroll
      for (int r = 0; r < 16; ++r) { acc10[r] = 0.f; acc11[r] = 0.f; }

      // ---- GEMM1: 16 sub-stages (K = 512) ----
#pragma unroll
      for (int ss = 0; ss < 16; ++ss) {
        issueStage(hc * 32 + ss + 2, is_); ADV3(is_);
        WAITVM(4); SCHEDB;
        const __bf16* rb = &Ring[w][cs][0]; ADV3(cs);
#pragma unroll
        for (int kk = 0; kk < 2; ++kk) {
          int koX = (ss * 2 + kk) * 2 + hi;
          bf16x8 a0 = *(const bf16x8*)&Xs[((size_t)lm * 64 + (koX ^ lm)) * 8];
          bf16x8 a1 = *(const bf16x8*)&Xs[((size_t)(32 + lm) * 64 + (koX ^ lm)) * 8];
          bf16x8 b  = *(const bf16x8*)&rb[kk * 512 + hi * 256 + lm * 8];
          acc10 = mfma32(a0, b, acc10);
          acc11 = mfma32(a1, b, acc11);
        }
      }

      // ---- bias + relu -> Hs (A-frag layout for GEMM2) ----
#pragma unroll
      for (int m = 0; m < 2; ++m)
#pragma unroll
        for (int r = 0; r < 16; ++r) {
          int tok = (r & 3) + 8 * (r >> 2) + 4 * hi + 32 * m;
          float v = fmaxf((m ? acc11[r] : acc10[r]) + bias, 0.f);
          int koW = (w * 4 + (lm >> 3)) ^ (tok & 31);
          Hs[((size_t)tok * 32 + koW) * 8 + (lm & 7)] = (__bf16)v;
        }
      WAITLGKM0; SBAR;                   // Hs ready for all waves

      // ---- GEMM2: 16 sub-stages (k-chunk of 256) ----
#pragma unroll
      for (int ss = 0; ss < 16; ++ss) {
        if (hc < 7 || ss < 14) { issueStage(hc * 32 + 16 + ss + 2, is_); ADV3(is_); }
        if (hc < 7 || ss < 14) { WAITVM(4); }
        else if (ss == 14)     { WAITVM(2); }
        else                   { WAITVM(0); }
        SCHEDB;
        const __bf16* rb = &Ring[w][cs][0]; ADV3(cs);
        int koH = ss * 2 + hi;
        bf16x8 h0  = *(const bf16x8*)&Hs[((size_t)lm * 32 + (koH ^ lm)) * 8];
        bf16x8 h1  = *(const bf16x8*)&Hs[((size_t)(32 + lm) * 32 + (koH ^ lm)) * 8];
        bf16x8 b0  = *(const bf16x8*)&rb[hi * 256 + lm * 8];
        bf16x8 b1v = *(const bf16x8*)&rb[512 + hi * 256 + lm * 8];
        acc200 = mfma32(h0, b0, acc200);
        acc201 = mfma32(h1, b0, acc201);
        acc210 = mfma32(h0, b1v, acc210);
        acc211 = mfma32(h1, b1v, acc211);
      }
      SBAR;                              // all waves done reading Hs before rewrite
    }

    // ---- epilogue: gate-weighted atomic accumulate, d-coalesced ----
    {
      int d0 = (2 * w) * 32 + lm;
      int d1 = (2 * w + 1) * 32 + lm;
#pragma unroll
      for (int m = 0; m < 2; ++m)
#pragma unroll
        for (int r = 0; r < 16; ++r) {
          int row = (r & 3) + 8 * (r >> 2) + 4 * hi + 32 * m;
          int tk = toks[row];
          float gg = gates[row];
          float* op = out + (size_t)tk * DIM;
          atomicAdd(op + d0, gg * ((m ? acc201[r] : acc200[r]) + b2r0));
          atomicAdd(op + d1, gg * ((m ? acc211[r] : acc210[r]) + b2r1));
        }
    }
  }
}

extern "C" void kernel_launch(void* const* d_in, const int* in_sizes, int n_in,
                              void* d_out, int out_size, void* d_ws, size_t ws_size,
                              hipStream_t stream) {
  const float* x  = (const float*)d_in[0];
  const float* Wr = (const float*)d_in[1];
  const float* br = (const float*)d_in[2];
  const float* Wn = (const float*)d_in[3];
  const float* bn = (const float*)d_in[4];
  const float* W1 = (const float*)d_in[5];
  const float* b1 = (const float*)d_in[6];
  const float* W2 = (const float*)d_in[7];
  const float* b2 = (const float*)d_in[8];
  float* out = (float*)d_out;

  uint8_t* wsb = (uint8_t*)d_ws;
  int* counts   = (int*)(wsb);
  int* fill     = (int*)(wsb + 64);
  int* top_i    = (int*)(wsb + 128);      // 131072 B
  float* top_g  = (float*)(wsb + 131200); // 131072 B
  int* ltok     = (int*)(wsb + 262272);   // 133120 B (33280 slots, 64-align pad)
  float* lgate  = (float*)(wsb + 395392); // 133120 B
  __bf16* W1p   = (__bf16*)(wsb + 528896);            // 16 MB
  __bf16* W2p   = (__bf16*)(wsb + 528896 + 16777216); // 16 MB
  // total ws usage: 528896 + 2*16777216 = 34,083,328 bytes (~34.1 MB)

  hipMemsetAsync(out, 0, (size_t)out_size * sizeof(float), stream);
  hipMemsetAsync(wsb, 0, 128, stream);

  pack_bfrag32<<<2048, 256, 0, stream>>>(W1, W1p, DIM, HID);
  pack_bfrag32<<<2048, 256, 0, stream>>>(W2, W2p, HID, DIM);
  router_kernel<<<T_TOKENS / 16, 256, 0, stream>>>(x, Wr, br, Wn, bn, counts, top_i, top_g);
  scatter_kernel<<<(2 * T_TOKENS) / 256, 256, 0, stream>>>(top_i, top_g, counts, fill, ltok, lgate);
  expert_mfma<<<512, 512, 0, stream>>>(x, W1p, b1, W2p, b2, counts, ltok, lgate, out);
}